// Round 1
// baseline (449.671 us; speedup 1.0000x reference)
//
#include <hip/hip_runtime.h>
#include <hip/hip_bf16.h>

#define NN 131072
#define KK 27
#define CC 32
#define EPSV 1e-5f

typedef __bf16 bf16x8 __attribute__((ext_vector_type(8)));
typedef short s16x8 __attribute__((ext_vector_type(8)));
typedef float f32x4 __attribute__((ext_vector_type(4)));

__device__ inline unsigned short f2bf(float f) {
    unsigned int u = __float_as_uint(f);
    u += 0x7FFF + ((u >> 16) & 1);   // round-to-nearest-even
    return (unsigned short)(u >> 16);
}

// One block = 256 threads = 4 waves; each wave owns 32 nodes (2 MFMA row-groups).
// Block builds all 27 taps' B-fragments (bf16) in LDS once, then loops taps.
__global__ __launch_bounds__(256) void scatter_kernel(
    const float* __restrict__ data, const float* __restrict__ weight,
    const int* __restrict__ neigh, float* __restrict__ out)
{
    __shared__ unsigned short wfrag[KK * 2 * 64 * 8];   // 55296 B: [k][chalf][lane][j]

    const int tid = threadIdx.x;
    const int lane = tid & 63;
    const int wv = tid >> 6;
    const int node_base = blockIdx.x * 128;

    // ---- Build B-fragments from f32 weight [K][CIN][COUT] (coalesced read) ----
    for (int p = tid; p < KK * 1024; p += 256) {
        const int k  = p >> 10;
        const int ci = (p >> 5) & 31;
        const int c  = p & 31;
        const unsigned short v = f2bf(weight[p]);
        // B-frag layout for 16x16x32: lane = (n&15) | (quad<<4), holds B[quad*8+j][n]
        const int chalf = c >> 4;
        const int fl = (c & 15) | ((ci >> 3) << 4);
        const int j = ci & 7;
        wfrag[(((k << 1) | chalf) * 64 + fl) * 8 + j] = v;
    }

    // ---- A-fragments: A[m=lane&15][kel=quad*8+j], converted f32->bf16 inline ----
    const int quad = lane >> 4;
    const int m = lane & 15;
    s16x8 afr[2];
    #pragma unroll
    for (int g = 0; g < 2; ++g) {
        const int node = node_base + wv * 32 + g * 16 + m;
        const float* src = data + node * 32 + quad * 8;
        const float4 v0 = *(const float4*)(src);
        const float4 v1 = *(const float4*)(src + 4);
        s16x8 s;
        s[0] = (short)f2bf(v0.x); s[1] = (short)f2bf(v0.y);
        s[2] = (short)f2bf(v0.z); s[3] = (short)f2bf(v0.w);
        s[4] = (short)f2bf(v1.x); s[5] = (short)f2bf(v1.y);
        s[6] = (short)f2bf(v1.z); s[7] = (short)f2bf(v1.w);
        afr[g] = s;
    }

    __syncthreads();

    const int rq = quad << 2;           // C/D row base: row = rq + reg
    const f32x4 zero = {0.f, 0.f, 0.f, 0.f};

    for (int k = 0; k < KK; ++k) {
        // destination rows for this tap (broadcast across the 16 lanes of each quad)
        int nj[2][4];
        #pragma unroll
        for (int g = 0; g < 2; ++g)
            #pragma unroll
            for (int r = 0; r < 4; ++r) {
                const int node = node_base + wv * 32 + g * 16 + rq + r;
                nj[g][r] = neigh[node * KK + k];
            }
        #pragma unroll
        for (int ch = 0; ch < 2; ++ch) {
            const int t = (k << 1) | ch;
            const s16x8 bs = *(const s16x8*)&wfrag[(t * 64 + lane) * 8];
            const bf16x8 bfr = __builtin_bit_cast(bf16x8, bs);
            const int c = (ch << 4) | m;
            #pragma unroll
            for (int g = 0; g < 2; ++g) {
                f32x4 acc = __builtin_amdgcn_mfma_f32_16x16x32_bf16(
                    __builtin_bit_cast(bf16x8, afr[g]), bfr, zero, 0, 0, 0);
                #pragma unroll
                for (int r = 0; r < 4; ++r) {
                    // lanes 0-15 hit 16 consecutive floats of row nj[g][r]
                    __hip_atomic_fetch_add(&out[nj[g][r] * 32 + c], acc[r],
                                           __ATOMIC_RELAXED, __HIP_MEMORY_SCOPE_AGENT);
                }
            }
        }
    }
}

// Per-channel sum / sumsq over the accumulator. Block covers 512 rows.
__global__ __launch_bounds__(256) void stats_kernel(
    const float* __restrict__ out, float* __restrict__ stats)
{
    __shared__ float ls[256], ls2[256];
    const int tid = threadIdx.x;
    const int c = tid & 31, rg = tid >> 5;
    float s = 0.f, s2 = 0.f;
    const int row0 = blockIdx.x * 512;
    #pragma unroll 8
    for (int it = 0; it < 64; ++it) {
        const float v = out[(row0 + it * 8 + rg) * 32 + c];
        s += v; s2 += v * v;
    }
    ls[tid] = s; ls2[tid] = s2;
    __syncthreads();
    if (tid < 32) {
        float S = 0.f, S2 = 0.f;
        #pragma unroll
        for (int r = 0; r < 8; ++r) { S += ls[r * 32 + tid]; S2 += ls2[r * 32 + tid]; }
        __hip_atomic_fetch_add(&stats[tid],      S,  __ATOMIC_RELAXED, __HIP_MEMORY_SCOPE_AGENT);
        __hip_atomic_fetch_add(&stats[32 + tid], S2, __ATOMIC_RELAXED, __HIP_MEMORY_SCOPE_AGENT);
    }
}

// y = gamma*(x-mean)*rsqrt(var+eps)+beta, relu — in place, float4 per thread.
__global__ __launch_bounds__(256) void bn_relu_kernel(
    float* __restrict__ out, const float* __restrict__ stats,
    const float* __restrict__ gamma, const float* __restrict__ beta)
{
    __shared__ float sc[32], sh[32];
    const int tid = threadIdx.x;
    if (tid < 32) {
        const float mean = stats[tid] * (1.0f / NN);
        const float var  = stats[32 + tid] * (1.0f / NN) - mean * mean;
        const float s = gamma[tid] * rsqrtf(var + EPSV);
        sc[tid] = s;
        sh[tid] = beta[tid] - mean * s;
    }
    __syncthreads();
    const int idx = blockIdx.x * 256 + tid;
    float4 v = ((float4*)out)[idx];
    const int cb = (idx & 7) << 2;      // 32 floats per row = 8 float4
    v.x = fmaxf(v.x * sc[cb]     + sh[cb],     0.f);
    v.y = fmaxf(v.y * sc[cb + 1] + sh[cb + 1], 0.f);
    v.z = fmaxf(v.z * sc[cb + 2] + sh[cb + 2], 0.f);
    v.w = fmaxf(v.w * sc[cb + 3] + sh[cb + 3], 0.f);
    ((float4*)out)[idx] = v;
}

extern "C" void kernel_launch(void* const* d_in, const int* in_sizes, int n_in,
                              void* d_out, int out_size, void* d_ws, size_t ws_size,
                              hipStream_t stream) {
    const float* data   = (const float*)d_in[0];
    const float* weight = (const float*)d_in[1];
    const float* gamma  = (const float*)d_in[2];
    const float* beta   = (const float*)d_in[3];
    const int*   neigh  = (const int*)d_in[4];
    float* out = (float*)d_out;
    float* stats = (float*)d_ws;          // 64 floats of scratch

    hipMemsetAsync(out, 0, (size_t)NN * CC * sizeof(float), stream);
    hipMemsetAsync(stats, 0, 64 * sizeof(float), stream);

    scatter_kernel<<<NN / 128, 256, 0, stream>>>(data, weight, neigh, out);
    stats_kernel<<<NN / 512, 256, 0, stream>>>(out, stats);
    bn_relu_kernel<<<(NN * CC / 4) / 256, 256, 0, stream>>>(out, stats, gamma, beta);
}